// Round 1
// baseline (7847.543 us; speedup 1.0000x reference)
//
#include <hip/hip_runtime.h>
#include <math.h>

// 4-layer LSTM (15/20/30/40), B=8192, T=512, fp32.
// Design: 16 lanes per batch element (unit-parallel), 32 elements per
// 512-thread block, 256 blocks = 1 block/CU, 2 waves/SIMD. Weights packed
// into LDS once per block; h state per element in LDS (wave-internal
// broadcast, no barriers in the main loop); c state + gate accs in registers.
// Output staged in LDS, flushed coalesced every 64 timesteps.

#define TSTEPS 512
#define NB     8192
#define INDIM  7
#define D1 15
#define D2 20
#define D3 30
#define D4 40

// packed weight row strides (floats): [Wih | zero-pad | Whh | bias | zero]
// chosen %32 in {4,12,20,28} so lane-row stride maps 16 lanes onto banks
// with only 2-way aliasing (free per m136)
#define S1 28
#define S2 44
#define S3 52
#define S4 76
// float4-chunks per gate row actually multiplied
#define CH1 6
#define CH2 10
#define CH3 13
#define CH4 19
// gate stride within a layer's packed weights (floats)
#define GS1 (D1*S1)
#define GS2 (D2*S2)
#define GS3 (D3*S3)
#define GS4 (D4*S4)

#define NE 32     // elements per block
#define NT 512    // threads per block

#define W1SZ (4*D1*S1)   // 1680 floats
#define W2SZ (4*D2*S2)   // 3520
#define W3SZ (4*D3*S3)   // 6240
#define W4SZ (4*D4*S4)   // 12160
// per-element h layout: [h1(15)+pad | h2(20) | h3(30)+2pad | h4(40)] = 108
#define HSTR 108
#define HO1 0
#define HO2 16
#define HO3 36
#define HO4 68

__device__ __forceinline__ float sigm(float x)  { return 1.0f / (1.0f + expf(-x)); }
__device__ __forceinline__ float tanhp(float x) { return 1.0f - 2.0f / (expf(2.0f * x) + 1.0f); }

__device__ __forceinline__ float cell_up(float ai, float af, float ag, float ao, float& c) {
  float ii = sigm(ai);
  float ff = sigm(af);
  float gg = tanhp(ag);
  float oo = sigm(ao);
  float cn = fmaf(ff, c, ii * gg);
  c = cn;
  return oo * tanhp(cn);
}

// read NQ float4s from LDS into iv[DST..] (all indices compile-time)
template<int NQ, int DST, int N>
__device__ __forceinline__ void ldh(float (&iv)[N], const float* src) {
#pragma unroll
  for (int q = 0; q < NQ; ++q) {
    float4 v = *(const float4*)(src + 4 * q);
    iv[DST + 4*q + 0] = v.x;
    iv[DST + 4*q + 1] = v.y;
    iv[DST + 4*q + 2] = v.z;
    iv[DST + 4*q + 3] = v.w;
  }
}

// 4 gate-row dot products (i,f,g,o) against iv; w = row base for this unit,
// gates at compile-time offsets GS apart -> ds_read_b128 with imm offsets.
template<int CH, int GS, int N>
__device__ __forceinline__ void dot4(const float* w, const float (&iv)[N],
                                     float& a0, float& a1, float& a2, float& a3) {
#pragma unroll
  for (int c = 0; c < CH; ++c) {
    float4 q0 = *(const float4*)(w + 0 * GS + 4 * c);
    float4 q1 = *(const float4*)(w + 1 * GS + 4 * c);
    float4 q2 = *(const float4*)(w + 2 * GS + 4 * c);
    float4 q3 = *(const float4*)(w + 3 * GS + 4 * c);
    a0 = fmaf(q0.x, iv[4*c+0], a0);
    a1 = fmaf(q1.x, iv[4*c+0], a1);
    a2 = fmaf(q2.x, iv[4*c+0], a2);
    a3 = fmaf(q3.x, iv[4*c+0], a3);
    a0 = fmaf(q0.y, iv[4*c+1], a0);
    a1 = fmaf(q1.y, iv[4*c+1], a1);
    a2 = fmaf(q2.y, iv[4*c+1], a2);
    a3 = fmaf(q3.y, iv[4*c+1], a3);
    a0 = fmaf(q0.z, iv[4*c+2], a0);
    a1 = fmaf(q1.z, iv[4*c+2], a1);
    a2 = fmaf(q2.z, iv[4*c+2], a2);
    a3 = fmaf(q3.z, iv[4*c+2], a3);
    a0 = fmaf(q0.w, iv[4*c+3], a0);
    a1 = fmaf(q1.w, iv[4*c+3], a1);
    a2 = fmaf(q2.w, iv[4*c+3], a2);
    a3 = fmaf(q3.w, iv[4*c+3], a3);
  }
}

__device__ __forceinline__ void stage_layer(float* dst, const float* Wih, const float* Whh,
                                            const float* bih, const float* bhh,
                                            int rows, int din, int ho, int dh, int bcol,
                                            int stride, int tid) {
  for (int idx = tid; idx < rows * stride; idx += NT) {
    int r = idx / stride;
    int c = idx - r * stride;
    float v = 0.0f;
    if (c < din)                    v = Wih[r * din + c];
    else if (c >= ho && c < ho+dh)  v = Whh[r * dh + (c - ho)];
    else if (c == bcol)             v = bih[r] + bhh[r];
    dst[idx] = v;
  }
}

__global__ void __launch_bounds__(NT, 2)
lstm_fused(const float* __restrict__ x,
           const float* __restrict__ Wih1, const float* __restrict__ Whh1,
           const float* __restrict__ bih1, const float* __restrict__ bhh1,
           const float* __restrict__ Wih2, const float* __restrict__ Whh2,
           const float* __restrict__ bih2, const float* __restrict__ bhh2,
           const float* __restrict__ Wih3, const float* __restrict__ Whh3,
           const float* __restrict__ bih3, const float* __restrict__ bhh3,
           const float* __restrict__ Wih4, const float* __restrict__ Whh4,
           const float* __restrict__ bih4, const float* __restrict__ bhh4,
           const float* __restrict__ Wl, const float* __restrict__ bl,
           float* __restrict__ out) {
  __shared__ __align__(16) float w1[W1SZ];
  __shared__ __align__(16) float w2[W2SZ];
  __shared__ __align__(16) float w3[W3SZ];
  __shared__ __align__(16) float w4[W4SZ];
  __shared__ __align__(16) float hs[NE][HSTR];
  __shared__ __align__(16) float obuf[NE][64];

  const int tid = threadIdx.x;

  // ---- one-time weight staging (packed+padded) + h-state zero ----
  stage_layer(w1, Wih1, Whh1, bih1, bhh1, 4*D1, INDIM, 8,  D1, 23, S1, tid);
  stage_layer(w2, Wih2, Whh2, bih2, bhh2, 4*D2, D1,    16, D2, 36, S2, tid);
  stage_layer(w3, Wih3, Whh3, bih3, bhh3, 4*D3, D2,    20, D3, 50, S3, tid);
  stage_layer(w4, Wih4, Whh4, bih4, bhh4, 4*D4, D3,    32, D4, 72, S4, tid);
  for (int i = tid; i < NE * HSTR; i += NT) (&hs[0][0])[i] = 0.0f;
  __syncthreads();  // only barrier in the kernel

  const int g   = tid >> 4;   // element group within block
  const int sub = tid & 15;   // lane within group
  const long b  = (long)blockIdx.x * NE + g;
  const float* __restrict__ xr = x + b * (TSTEPS * INDIM);
  float* hme  = hs[g];
  float* ob   = obuf[g];
  float* outp = out + b * TSTEPS;

  // cell state in registers (owned units per lane)
  float c1 = 0.f;
  float c2a = 0.f, c2b = 0.f;
  float c3a = 0.f, c3b = 0.f;
  float c4a = 0.f, c4b = 0.f, c4c = 0.f;

  const float wla = Wl[sub];
  const float wlb = Wl[sub + 16];
  const float wlc = (sub + 32 < D4) ? Wl[sub + 32] : 0.0f;
  const float blv = bl[0];

  // clamped unit indices (inactive lanes compute a duplicate, never commit)
  const int u1  = (sub < D1)      ? sub        : (D1 - 1);
  const int u2b = (sub + 16 < D2) ? (sub + 16) : (D2 - 1);
  const int u3b = (sub + 16 < D3) ? (sub + 16) : (D3 - 1);
  const int u4c = (sub + 32 < D4) ? (sub + 32) : (D4 - 1);

  const float* w1p  = w1 + u1 * S1;
  const float* w2pa = w2 + sub * S2;
  const float* w2pb = w2 + u2b * S2;
  const float* w3pa = w3 + sub * S3;
  const float* w3pb = w3 + u3b * S3;
  const float* w4pa = w4 + sub * S4;
  const float* w4pb = w4 + (sub + 16) * S4;
  const float* w4pc = w4 + u4c * S4;

  // prefetch x for t=0
  float nx0 = xr[0], nx1 = xr[1], nx2 = xr[2], nx3 = xr[3],
        nx4 = xr[4], nx5 = xr[5], nx6 = xr[6];

#pragma unroll 1
  for (int t = 0; t < TSTEPS; ++t) {
    float x0 = nx0, x1 = nx1, x2 = nx2, x3 = nx3, x4 = nx4, x5 = nx5, x6 = nx6;
    if (t + 1 < TSTEPS) {  // issue next-step x loads early; consumed next iter
      const float* nxr = xr + (t + 1) * INDIM;
      nx0 = nxr[0]; nx1 = nxr[1]; nx2 = nxr[2]; nx3 = nxr[3];
      nx4 = nxr[4]; nx5 = nxr[5]; nx6 = nxr[6];
    }

    // ---------- layer 1: iv = [x(7) | 0 | h1(15) | 1] ----------
    float iv1[24];
    iv1[0]=x0; iv1[1]=x1; iv1[2]=x2; iv1[3]=x3; iv1[4]=x4; iv1[5]=x5; iv1[6]=x6;
    iv1[7] = 0.0f;
    ldh<4, 8>(iv1, hme + HO1);   // h1 prev -> [8..23] ([23] = pad, overwritten)
    iv1[23] = 1.0f;
    float a0=0.f,a1=0.f,a2=0.f,a3=0.f;
    dot4<CH1, GS1>(w1p, iv1, a0,a1,a2,a3);
    float h1n = cell_up(a0,a1,a2,a3, c1);
    if (sub < D1) hme[HO1 + sub] = h1n;

    // ---------- layer 2: iv = [h1(15) | 0 | h2(20) | 1 | 0..] ----------
    float iv2[40];
    ldh<4, 0>(iv2, hme + HO1);    // h1 NEW -> [0..15] ([15] = 0 pad)
    ldh<5, 16>(iv2, hme + HO2);   // h2 prev -> [16..35]
    iv2[36] = 1.0f; iv2[37] = 0.0f; iv2[38] = 0.0f; iv2[39] = 0.0f;
    float b0=0.f,b1=0.f,b2=0.f,b3=0.f, d0=0.f,d1=0.f,d2=0.f,d3=0.f;
    dot4<CH2, GS2>(w2pa, iv2, b0,b1,b2,b3);
    dot4<CH2, GS2>(w2pb, iv2, d0,d1,d2,d3);
    float h2na = cell_up(b0,b1,b2,b3, c2a);
    float h2nb = cell_up(d0,d1,d2,d3, c2b);
    hme[HO2 + sub] = h2na;
    if (sub + 16 < D2) hme[HO2 + sub + 16] = h2nb;

    // ---------- layer 3: iv = [h2(20) | h3(30) | 1 | 0] ----------
    float iv3[52];
    ldh<5, 0>(iv3, hme + HO2);    // h2 NEW -> [0..19]
    ldh<8, 20>(iv3, hme + HO3);   // h3 prev -> [20..51] ([50..51] pads)
    iv3[50] = 1.0f; iv3[51] = 0.0f;
    float e0=0.f,e1=0.f,e2=0.f,e3=0.f, f0=0.f,f1=0.f,f2=0.f,f3=0.f;
    dot4<CH3, GS3>(w3pa, iv3, e0,e1,e2,e3);
    dot4<CH3, GS3>(w3pb, iv3, f0,f1,f2,f3);
    float h3na = cell_up(e0,e1,e2,e3, c3a);
    float h3nb = cell_up(f0,f1,f2,f3, c3b);
    hme[HO3 + sub] = h3na;
    if (sub + 16 < D3) hme[HO3 + sub + 16] = h3nb;

    // ---------- layer 4: iv = [h3(30) | 0,0 | h4(40) | 1 | 0..] ----------
    float iv4[76];
    ldh<8, 0>(iv4, hme + HO3);    // h3 NEW -> [0..31] ([30..31] = 0 pads)
    ldh<10, 32>(iv4, hme + HO4);  // h4 prev -> [32..71]
    iv4[72] = 1.0f; iv4[73] = 0.0f; iv4[74] = 0.0f; iv4[75] = 0.0f;
    float p0=0.f,p1=0.f,p2=0.f,p3=0.f;
    float q0=0.f,q1=0.f,q2=0.f,q3=0.f;
    float r0=0.f,r1=0.f,r2=0.f,r3=0.f;
    dot4<CH4, GS4>(w4pa, iv4, p0,p1,p2,p3);
    dot4<CH4, GS4>(w4pb, iv4, q0,q1,q2,q3);
    dot4<CH4, GS4>(w4pc, iv4, r0,r1,r2,r3);
    float h4na = cell_up(p0,p1,p2,p3, c4a);
    float h4nb = cell_up(q0,q1,q2,q3, c4b);
    float h4nc = cell_up(r0,r1,r2,r3, c4c);
    hme[HO4 + sub] = h4na;
    hme[HO4 + sub + 16] = h4nb;
    if (sub + 32 < D4) hme[HO4 + sub + 32] = h4nc;

    // ---------- output: dot(h4, Wl) + bl ----------
    float part = fmaf(h4na, wla, fmaf(h4nb, wlb, h4nc * wlc));  // wlc=0 if inactive
    part += __shfl_xor(part, 8);
    part += __shfl_xor(part, 4);
    part += __shfl_xor(part, 2);
    part += __shfl_xor(part, 1);
    if (sub == 0) ob[t & 63] = part + blv;
    if ((t & 63) == 63) {  // coalesced flush of 64 timesteps
      float4 v = *(const float4*)(ob + (sub << 2));
      *(float4*)(outp + (t - 63) + (sub << 2)) = v;
    }
  }
}

extern "C" void kernel_launch(void* const* d_in, const int* in_sizes, int n_in,
                              void* d_out, int out_size, void* d_ws, size_t ws_size,
                              hipStream_t stream) {
  lstm_fused<<<dim3(NB / NE), dim3(NT), 0, stream>>>(
      (const float*)d_in[0],
      (const float*)d_in[1],  (const float*)d_in[2],  (const float*)d_in[3],  (const float*)d_in[4],
      (const float*)d_in[5],  (const float*)d_in[6],  (const float*)d_in[7],  (const float*)d_in[8],
      (const float*)d_in[9],  (const float*)d_in[10], (const float*)d_in[11], (const float*)d_in[12],
      (const float*)d_in[13], (const float*)d_in[14], (const float*)d_in[15], (const float*)d_in[16],
      (const float*)d_in[17], (const float*)d_in[18],
      (float*)d_out);
}